// Round 7
// baseline (4177.680 us; speedup 1.0000x reference)
//
#include <hip/hip_runtime.h>

// InverseRecurrentLayer: 512-step scan  state = tanh(h_t + state@Wt + bias),
// Wt alternating every 64 steps between inv(W)=W^T (orthogonal) and W.
// v7: (a) __launch_bounds__(512,2) -> 256-VGPR cap, W-fragments stay in registers
//     (v6 spilled: 160 live VGPR vs 128 allocated -> per-step scratch refills);
// (b) h = inputs@R hoisted out of the scan into a per-block prepass written to
//     d_out itself (h_all shape == out shape; each block writes/reads only its own
//     slice -> no coherence traffic), scan epilogue adds prefetched h scalars.

#define NTHR 512
#define TSTEPS 512

typedef __attribute__((ext_vector_type(4))) float f32x4;
typedef __attribute__((ext_vector_type(8))) _Float16 f16x8;
typedef unsigned long long u64;
typedef unsigned int u32;

union pk2 { _Float16 h[2]; u32 u; };

__device__ __forceinline__ f32x4 mfma16(f16x8 a, f16x8 b, f32x4 c){
  return __builtin_amdgcn_mfma_f32_16x16x32_f16(a, b, c, 0, 0, 0);
}

// 16-block group barrier (r4/r6-proven flag-array pattern, scoped to row-group)
__device__ __forceinline__ void gbar(unsigned* gflags, int cblk, unsigned gen){
  __syncthreads();                // drains vmcnt: state stores committed before flag
  if (threadIdx.x == 0)
    __hip_atomic_store(gflags + cblk, gen, __ATOMIC_RELAXED, __HIP_MEMORY_SCOPE_AGENT);
  if (threadIdx.x < 64){
    const int src = (threadIdx.x < 16) ? threadIdx.x : 0;
    for (;;){
      unsigned v = __hip_atomic_load(gflags + src, __ATOMIC_RELAXED, __HIP_MEMORY_SCOPE_AGENT);
      if (__all((int)(v >= gen))) break;
      __builtin_amdgcn_s_sleep(1);
    }
  }
  __syncthreads();
  asm volatile("" ::: "memory");
}

// input projection partial for step t: this wave's K=256 slice of F=512
__device__ __forceinline__ f32x4 input_accum(const float* __restrict__ inputs,
                                             const f16x8 (&rf)[8],
                                             int t, int r0, int kg, int lr, int lg){
  f32x4 acc = {0.f, 0.f, 0.f, 0.f};
  const float* base = inputs + ((size_t)(r0 + lr) * 512 + (size_t)t) * 512 + kg*256 + lg*8;
  #pragma unroll
  for (int i = 0; i < 8; ++i){
    float4 xa = *(const float4*)(base + i*32);
    float4 xb = *(const float4*)(base + i*32 + 4);
    f16x8 a;
    a[0]=(_Float16)xa.x; a[1]=(_Float16)xa.y; a[2]=(_Float16)xa.z; a[3]=(_Float16)xa.w;
    a[4]=(_Float16)xb.x; a[5]=(_Float16)xb.y; a[6]=(_Float16)xb.z; a[7]=(_Float16)xb.w;
    acc = mfma16(a, rf[i], acc);
  }
  return acc;
}

__global__ __launch_bounds__(NTHR, 2) void irl_scan(
    const float* __restrict__ inputs, const float* __restrict__ R,
    const float* __restrict__ W, const float* __restrict__ bias,
    const float* __restrict__ x0, float* __restrict__ out,
    unsigned short* __restrict__ st,   // 2 x [64][1024] fp16 state (ping-pong)
    unsigned* __restrict__ flags)
{
  __shared__ char  alds[16 * 2048];     // row-group state [16][1024] fp16, XOR-swizzled
  __shared__ float red[2][4][16][16];   // kg=1 partials, parity-buffered

  const int tid = threadIdx.x;
  const int w   = tid >> 6;          // 8 waves
  const int n   = w & 3;             // N-tile (16 cols each)
  const int kg  = w >> 2;            // K-half (512 each)
  const int l   = tid & 63;
  const int lr  = l & 15;            // A row / B col / D col
  const int lg  = l >> 4;            // k-subgroup / D row-subgroup
  const int cblk = blockIdx.x & 15;  // col-split
  const int grp  = blockIdx.x >> 4;  // row-group
  const int col0 = cblk << 6;        // 64 unit-columns per block
  const int r0   = grp << 4;         // 16 batch rows per block
  const int u    = col0 + n*16 + lr;
  const float bias_u = bias[u];
  unsigned* gflags = flags + grp*64;

  // ---- state[0] <- x0 : 16 rows x 32 col-pairs, packed u32 atomic stores ----
  {
    const int row = tid >> 5, cp = tid & 31;
    pk2 p;
    p.h[0] = (_Float16)x0[col0 + 2*cp];
    p.h[1] = (_Float16)x0[col0 + 2*cp + 1];
    __hip_atomic_store((u32*)st + (size_t)(r0 + row)*512 + (col0 >> 1) + cp, p.u,
                       __ATOMIC_RELAXED, __HIP_MEMORY_SCOPE_AGENT);
  }

  // ---- R fragments (prepass only) ----
  {
    f16x8 rf[8];
    #pragma unroll
    for (int i = 0; i < 8; ++i){
      const int f = kg*256 + i*32 + lg*8;
      f16x8 tv;
      #pragma unroll
      for (int j = 0; j < 8; ++j)
        tv[j] = (_Float16)R[(size_t)(f + j)*1024 + u];
      rf[i] = tv;
    }

    // ---- PREPASS: h[t, r0+row, u] = (inputs @ R) into d_out (own slice only) ----
    for (int t = 0; t < TSTEPS; ++t){
      f32x4 a = input_accum(inputs, rf, t, r0, kg, lr, lg);
      const int par = t & 1;
      if (kg == 1){
        #pragma unroll
        for (int j = 0; j < 4; ++j)
          red[par][n][lg*4 + j][lr] = a[j];
      }
      __syncthreads();
      if (kg == 0){
        #pragma unroll
        for (int j = 0; j < 4; ++j){
          const int row = lg*4 + j;
          out[(size_t)t*65536 + (size_t)(r0 + row)*1024 + u]
            = a[j] + red[par][n][row][lr];
        }
      }
      // parity double-buffer: red[par] next written at t+2, after >=1 barrier
    }
  }

  // ---- W fragments, BOTH phases, in registers (loaded after prepass) ----
  f16x8 wf0[16], wf1[16];              // wf0: inv(W)=W^T, wf1: W
  #pragma unroll
  for (int i = 0; i < 16; ++i){
    const int k = kg*512 + i*32 + lg*8;
    f16x8 t0, t1;
    #pragma unroll
    for (int j = 0; j < 8; ++j){
      t0[j] = (_Float16)W[(size_t)u*1024 + (k + j)];     // W^T: B[n][k] = W[u][k]
      t1[j] = (_Float16)W[(size_t)(k + j)*1024 + u];     // W:   B[n][k] = W[k][u]
    }
    wf0[i] = t0; wf1[i] = t1;
  }

  gbar(gflags, cblk, 1u);

  unsigned cur = 0;
  for (int t = 0; t < TSTEPS; ++t){
    const int ph = (t >> 6) & 1;     // 1 -> W, 0 -> inv(W)=W^T

    // prefetch this step's h (written by this very block in the prepass)
    float hv[4];
    if (kg == 0){
      #pragma unroll
      for (int j = 0; j < 4; ++j)
        hv[j] = out[(size_t)t*65536 + (size_t)(r0 + lg*4 + j)*1024 + u];
    }

    // ---- stage row-group state into LDS: 4096 x 8B atomic loads (8/thread) ----
    const u64* sb = (const u64*)(st + ((size_t)cur << 16));
    #pragma unroll
    for (int j = 0; j < 8; ++j){
      const int idx = tid + j*512;
      const int row = idx >> 8, kc = idx & 255;
      u64 q = __hip_atomic_load(sb + (size_t)(r0 + row)*256 + kc,
                                __ATOMIC_RELAXED, __HIP_MEMORY_SCOPE_AGENT);
      *(u64*)(alds + row*2048 + ((kc*8) ^ ((row & 7) << 4))) = q;
    }
    __syncthreads();

    // ---- recurrent GEMM: 16 MFMAs over this wave's K-half ----
    f32x4 acc = {0.f, 0.f, 0.f, 0.f};
    const int kb0 = kg*1024 + lg*16;
    if (ph){
      #pragma unroll
      for (int i = 0; i < 16; ++i){
        f16x8 a = *(const f16x8*)(alds + lr*2048 + ((kb0 + i*64) ^ ((lr & 7) << 4)));
        acc = mfma16(a, wf1[i], acc);
      }
    } else {
      #pragma unroll
      for (int i = 0; i < 16; ++i){
        f16x8 a = *(const f16x8*)(alds + lr*2048 + ((kb0 + i*64) ^ ((lr & 7) << 4)));
        acc = mfma16(a, wf0[i], acc);
      }
    }

    // ---- kg reduction (2-way) via LDS ----
    const int par = t & 1;
    if (kg == 1){
      #pragma unroll
      for (int j = 0; j < 4; ++j)
        red[par][n][lg*4 + j][lr] = acc[j];
    }
    __syncthreads();

    if (kg == 0){
      unsigned* nb = (unsigned*)(st + ((size_t)(cur ^ 1u) << 16));
      #pragma unroll
      for (int j = 0; j < 4; ++j){
        const int row = lg*4 + j;
        const float v = tanhf(acc[j] + red[par][n][row][lr] + hv[j] + bias_u);
        __builtin_nontemporal_store(v, out + (size_t)t*65536 + (size_t)(r0 + row)*1024 + u);
        pk2 me; me.h[0] = (_Float16)v; me.h[1] = (_Float16)0.f;
        const u32 other = (u32)__shfl_xor((int)me.u, 1);
        if (!(lr & 1))
          __hip_atomic_store(nb + (size_t)(r0 + row)*512 + (u >> 1),
                             (me.u & 0xffffu) | (other << 16),
                             __ATOMIC_RELAXED, __HIP_MEMORY_SCOPE_AGENT);
      }
    }

    cur ^= 1u;
    if (t < TSTEPS - 1)
      gbar(gflags, cblk, (unsigned)(t + 2));
  }
}

extern "C" void kernel_launch(void* const* d_in, const int* in_sizes, int n_in,
                              void* d_out, int out_size, void* d_ws, size_t ws_size,
                              hipStream_t stream){
  (void)in_sizes; (void)n_in; (void)out_size; (void)ws_size;
  const float* inputs = (const float*)d_in[0];   // [64,512,512] f32
  const float* R      = (const float*)d_in[1];   // [512,1024]  f32
  const float* W      = (const float*)d_in[2];   // [1024,1024] f32
  const float* bias   = (const float*)d_in[3];   // [1024]      f32
  const float* x0     = (const float*)d_in[4];   // [1024]      f32
  float* out = (float*)d_out;                    // [512,64,1024] f32 (h, then states)

  char* ws = (char*)d_ws;
  unsigned* flags = (unsigned*)ws;                       // 4KB (4 groups x 256B)
  unsigned short* st = (unsigned short*)(ws + 4096);     // 2 x 64x1024 fp16

  hipMemsetAsync(flags, 0, 4096, stream);
  hipLaunchKernelGGL(irl_scan, dim3(64), dim3(NTHR), 0, stream,
                     inputs, R, W, bias, x0, out, st, flags);
}

// Round 8
// 3638.759 us; speedup vs baseline: 1.1481x; 1.1481x over previous
//
#include <hip/hip_runtime.h>

// InverseRecurrentLayer: 512-step scan  state = tanh(h_t + state@Wt + bias),
// Wt alternating every 64 steps between inv(W)=W^T (orthogonal) and W.
// v8: register-pressure fix. v6/v7 kept BOTH phases' W-fragments live (128 VGPR)
// in a 128-VGPR allocation -> compiler spilled/sank W loads into the scan loop
// (~400MB of FETCH residue). Now only the CURRENT phase's wf[16] (64 VGPR) is
// live, reloaded at the 8 phase switches. Stage loads batched (8 in flight).
// h-prefetch moved between barrier arrive and poll to hide under the wait.

#define NTHR 512
#define TSTEPS 512

typedef __attribute__((ext_vector_type(4))) float f32x4;
typedef __attribute__((ext_vector_type(8))) _Float16 f16x8;
typedef unsigned long long u64;
typedef unsigned int u32;

union pk2 { _Float16 h[2]; u32 u; };

__device__ __forceinline__ f32x4 mfma16(f16x8 a, f16x8 b, f32x4 c){
  return __builtin_amdgcn_mfma_f32_16x16x32_f16(a, b, c, 0, 0, 0);
}

// 16-block group barrier (r4/r6-proven flag-array pattern, scoped to row-group)
__device__ __forceinline__ void gbar(unsigned* gflags, int cblk, unsigned gen){
  __syncthreads();
  if (threadIdx.x == 0)
    __hip_atomic_store(gflags + cblk, gen, __ATOMIC_RELAXED, __HIP_MEMORY_SCOPE_AGENT);
  if (threadIdx.x < 64){
    const int src = (threadIdx.x < 16) ? threadIdx.x : 0;
    for (;;){
      unsigned v = __hip_atomic_load(gflags + src, __ATOMIC_RELAXED, __HIP_MEMORY_SCOPE_AGENT);
      if (__all((int)(v >= gen))) break;
      __builtin_amdgcn_s_sleep(1);
    }
  }
  __syncthreads();
  asm volatile("" ::: "memory");
}

// input projection partial for step t: this wave's K=256 slice of F=512
__device__ __forceinline__ f32x4 input_accum(const float* __restrict__ inputs,
                                             const f16x8 (&rf)[8],
                                             int t, int r0, int kg, int lr, int lg){
  f32x4 acc = {0.f, 0.f, 0.f, 0.f};
  const float* base = inputs + ((size_t)(r0 + lr) * 512 + (size_t)t) * 512 + kg*256 + lg*8;
  #pragma unroll
  for (int i = 0; i < 8; ++i){
    float4 xa = *(const float4*)(base + i*32);
    float4 xb = *(const float4*)(base + i*32 + 4);
    f16x8 a;
    a[0]=(_Float16)xa.x; a[1]=(_Float16)xa.y; a[2]=(_Float16)xa.z; a[3]=(_Float16)xa.w;
    a[4]=(_Float16)xb.x; a[5]=(_Float16)xb.y; a[6]=(_Float16)xb.z; a[7]=(_Float16)xb.w;
    acc = mfma16(a, rf[i], acc);
  }
  return acc;
}

__global__ __launch_bounds__(NTHR, 2) void irl_scan(
    const float* __restrict__ inputs, const float* __restrict__ R,
    const float* __restrict__ W, const float* __restrict__ bias,
    const float* __restrict__ x0, float* __restrict__ out,
    unsigned short* __restrict__ st,   // 2 x [64][1024] fp16 state (ping-pong)
    unsigned* __restrict__ flags)
{
  __shared__ char  alds[16 * 2048];     // row-group state [16][1024] fp16, XOR-swizzled
  __shared__ float red[2][4][16][16];   // kg=1 partials, parity-buffered

  const int tid = threadIdx.x;
  const int w   = tid >> 6;          // 8 waves
  const int n   = w & 3;             // N-tile (16 cols each)
  const int kg  = w >> 2;            // K-half (512 each)
  const int l   = tid & 63;
  const int lr  = l & 15;            // A row / B col / D col
  const int lg  = l >> 4;            // k-subgroup / D row-subgroup
  const int cblk = blockIdx.x & 15;  // col-split
  const int grp  = blockIdx.x >> 4;  // row-group
  const int col0 = cblk << 6;        // 64 unit-columns per block
  const int r0   = grp << 4;         // 16 batch rows per block
  const int u    = col0 + n*16 + lr;
  const float bias_u = bias[u];
  unsigned* gflags = flags + grp*64;

  // ---- state[0] <- x0 : 16 rows x 32 col-pairs, packed u32 atomic stores ----
  {
    const int row = tid >> 5, cp = tid & 31;
    pk2 p;
    p.h[0] = (_Float16)x0[col0 + 2*cp];
    p.h[1] = (_Float16)x0[col0 + 2*cp + 1];
    __hip_atomic_store((u32*)st + (size_t)(r0 + row)*512 + (col0 >> 1) + cp, p.u,
                       __ATOMIC_RELAXED, __HIP_MEMORY_SCOPE_AGENT);
  }

  // ---- R fragments (prepass only; dead afterwards) ----
  {
    f16x8 rf[8];
    #pragma unroll
    for (int i = 0; i < 8; ++i){
      const int f = kg*256 + i*32 + lg*8;
      f16x8 tv;
      #pragma unroll
      for (int j = 0; j < 8; ++j)
        tv[j] = (_Float16)R[(size_t)(f + j)*1024 + u];
      rf[i] = tv;
    }

    // ---- PREPASS: h[t, r0+row, u] = (inputs @ R) into d_out (own slice only) ----
    for (int t = 0; t < TSTEPS; ++t){
      f32x4 a = input_accum(inputs, rf, t, r0, kg, lr, lg);
      const int par = t & 1;
      if (kg == 1){
        #pragma unroll
        for (int j = 0; j < 4; ++j)
          red[par][n][lg*4 + j][lr] = a[j];
      }
      __syncthreads();
      if (kg == 0){
        #pragma unroll
        for (int j = 0; j < 4; ++j){
          const int row = lg*4 + j;
          out[(size_t)t*65536 + (size_t)(r0 + row)*1024 + u]
            = a[j] + red[par][n][row][lr];
        }
      }
    }
  }

  // h prefetch for t=0 (own block's prepass writes; same-block visibility)
  float hv[4];
  if (kg == 0){
    #pragma unroll
    for (int j = 0; j < 4; ++j)
      hv[j] = out[(size_t)(r0 + lg*4 + j)*1024 + u];
  }

  gbar(gflags, cblk, 1u);

  unsigned cur = 0;
  int pp = -1;
  f16x8 wf[16];                        // current phase only: 64 VGPRs
  for (int t = 0; t < TSTEPS; ++t){
    const int ph = (t >> 6) & 1;       // 1 -> W, 0 -> inv(W)=W^T
    if (ph != pp){
      pp = ph;
      if (ph){
        #pragma unroll
        for (int i = 0; i < 16; ++i){
          const int k = kg*512 + i*32 + lg*8;
          f16x8 tv;
          #pragma unroll
          for (int j = 0; j < 8; ++j)
            tv[j] = (_Float16)W[(size_t)(k + j)*1024 + u];   // W: B[n][k] = W[k][u]
          wf[i] = tv;
        }
      } else {
        #pragma unroll
        for (int i = 0; i < 16; ++i){
          const int k = kg*512 + i*32 + lg*8;
          f16x8 tv;
          #pragma unroll
          for (int j = 0; j < 8; ++j)
            tv[j] = (_Float16)W[(size_t)u*1024 + (k + j)];   // W^T: B[n][k] = W[u][k]
          wf[i] = tv;
        }
      }
    }

    // ---- stage row-group state into LDS: 8 atomic u64 loads batched in flight ----
    const u64* sb = (const u64*)(st + ((size_t)cur << 16));
    u64 q[8];
    #pragma unroll
    for (int j = 0; j < 8; ++j){
      const int idx = tid + j*512;
      q[j] = __hip_atomic_load(sb + (size_t)(r0 + (idx >> 8))*256 + (idx & 255),
                               __ATOMIC_RELAXED, __HIP_MEMORY_SCOPE_AGENT);
    }
    #pragma unroll
    for (int j = 0; j < 8; ++j){
      const int idx = tid + j*512;
      const int row = idx >> 8, kc = idx & 255;
      *(u64*)(alds + row*2048 + ((kc*8) ^ ((row & 7) << 4))) = q[j];
    }
    __syncthreads();

    // ---- recurrent GEMM: 16 MFMAs over this wave's K-half ----
    f32x4 acc = {0.f, 0.f, 0.f, 0.f};
    const int kb0 = kg*1024 + lg*16;
    #pragma unroll
    for (int i = 0; i < 16; ++i){
      f16x8 a = *(const f16x8*)(alds + lr*2048 + ((kb0 + i*64) ^ ((lr & 7) << 4)));
      acc = mfma16(a, wf[i], acc);
    }

    // ---- kg reduction (2-way) via LDS ----
    const int par = t & 1;
    if (kg == 1){
      #pragma unroll
      for (int j = 0; j < 4; ++j)
        red[par][n][lg*4 + j][lr] = acc[j];
    }
    __syncthreads();

    if (kg == 0){
      unsigned* nb = (unsigned*)(st + ((size_t)(cur ^ 1u) << 16));
      #pragma unroll
      for (int j = 0; j < 4; ++j){
        const int row = lg*4 + j;
        const float v = tanhf(acc[j] + red[par][n][row][lr] + hv[j] + bias_u);
        __builtin_nontemporal_store(v, out + (size_t)t*65536 + (size_t)(r0 + row)*1024 + u);
        pk2 me; me.h[0] = (_Float16)v; me.h[1] = (_Float16)0.f;
        const u32 other = (u32)__shfl_xor((int)me.u, 1);
        if (!(lr & 1))
          __hip_atomic_store(nb + (size_t)(r0 + row)*512 + (u >> 1),
                             (me.u & 0xffffu) | (other << 16),
                             __ATOMIC_RELAXED, __HIP_MEMORY_SCOPE_AGENT);
      }
    }

    cur ^= 1u;
    if (t < TSTEPS - 1){
      // ---- barrier, split: arrive -> prefetch hv(t+1) under the poll -> wait ----
      __syncthreads();               // all waves' state stores drained (vmcnt)
      if (tid == 0)
        __hip_atomic_store(gflags + cblk, (unsigned)(t + 2),
                           __ATOMIC_RELAXED, __HIP_MEMORY_SCOPE_AGENT);
      if (kg == 0){
        #pragma unroll
        for (int j = 0; j < 4; ++j)
          hv[j] = out[(size_t)(t + 1)*65536 + (size_t)(r0 + lg*4 + j)*1024 + u];
      }
      if (tid < 64){
        const int src = (tid < 16) ? tid : 0;
        for (;;){
          unsigned v = __hip_atomic_load(gflags + src, __ATOMIC_RELAXED, __HIP_MEMORY_SCOPE_AGENT);
          if (__all((int)(v >= (unsigned)(t + 2)))) break;
          __builtin_amdgcn_s_sleep(1);
        }
      }
      __syncthreads();
      asm volatile("" ::: "memory");
    }
  }
}

extern "C" void kernel_launch(void* const* d_in, const int* in_sizes, int n_in,
                              void* d_out, int out_size, void* d_ws, size_t ws_size,
                              hipStream_t stream){
  (void)in_sizes; (void)n_in; (void)out_size; (void)ws_size;
  const float* inputs = (const float*)d_in[0];   // [64,512,512] f32
  const float* R      = (const float*)d_in[1];   // [512,1024]  f32
  const float* W      = (const float*)d_in[2];   // [1024,1024] f32
  const float* bias   = (const float*)d_in[3];   // [1024]      f32
  const float* x0     = (const float*)d_in[4];   // [1024]      f32
  float* out = (float*)d_out;                    // [512,64,1024] f32 (h, then states)

  char* ws = (char*)d_ws;
  unsigned* flags = (unsigned*)ws;                       // 4KB (4 groups x 256B)
  unsigned short* st = (unsigned short*)(ws + 4096);     // 2 x 64x1024 fp16

  hipMemsetAsync(flags, 0, 4096, stream);
  hipLaunchKernelGGL(irl_scan, dim3(64), dim3(NTHR), 0, stream,
                     inputs, R, W, bias, x0, out, st, flags);
}